// Round 15
// baseline (602.810 us; speedup 1.0000x reference)
//
#include <hip/hip_runtime.h>
#include <hip/hip_bf16.h>
#include <stdint.h>

// Qwen3.5 MoE block: router top-2 sparse dispatch + shared expert (SwiGLU), bf16 MFMA.
// B=2,S=1024 -> TOK=2048 tokens. H=2048, I=1408, IS=5632, E=8, K=2. Output f32.
// Round 15: W5/W6 (down-weight) transposes INTERLEAVED with gateup GEMM blocks
// (stride-5 blockIdx: GEMM at b%5==0) -> co-resident on CUs (2x64KB GEMM + 16KB
// transpose fits 160KB LDS), ~207MB of HBM work hidden under compute-bound gateup.
// Serial transpose pass now covers only W1-W4. GEMM internals = round-10 exact.
#define TOK   2048
#define HDIM  2048
#define IDIM  1408
#define ISDIM 5632
#define NEXP  8

typedef float  f32x4  __attribute__((ext_vector_type(4)));
typedef short  bf16x8 __attribute__((ext_vector_type(8)));

__device__ __forceinline__ unsigned short f2b(float f) {
  union { float f; uint32_t u; } v; v.f = f;
  return (unsigned short)((v.u + 0x7fffu + ((v.u >> 16) & 1u)) >> 16); // RNE
}

// async global->LDS DMA, 16 B per lane: LDS dest wave-uniform base + lane*16.
__device__ __forceinline__ void async16(void* lds, const void* g) {
  __builtin_amdgcn_global_load_lds(
      (const __attribute__((address_space(1))) unsigned int*)g,
      (__attribute__((address_space(3))) unsigned int*)lds, 16, 0, 0);
}

// counted-vmcnt + raw barrier (no lgkm/vm drain); "memory" clobber pins LDS/VMEM ops.
#define VWAIT_BAR(N) asm volatile("s_waitcnt vmcnt(" #N ")\n\ts_barrier" ::: "memory")
#define VBAR()       asm volatile("s_barrier" ::: "memory")

// ---------------- router ----------------
__global__ __launch_bounds__(256) void router_kernel(
    const float* __restrict__ X, const float* __restrict__ GW,
    const float* __restrict__ SGW, int* __restrict__ cnt,
    int* __restrict__ tok_e, float* __restrict__ tok_w, float* __restrict__ sg)
{
  const int tkn = blockIdx.x, t = threadIdx.x;
  const float* xr = X + (size_t)tkn * HDIM;
  float a[NEXP + 1];
  #pragma unroll
  for (int e = 0; e <= NEXP; ++e) a[e] = 0.f;
  for (int h = t; h < HDIM; h += 256) {
    const float xv = xr[h];
    #pragma unroll
    for (int e = 0; e < NEXP; ++e) a[e] += xv * GW[e * HDIM + h];
    a[NEXP] += xv * SGW[h];
  }
  #pragma unroll
  for (int off = 32; off > 0; off >>= 1) {
    #pragma unroll
    for (int e = 0; e <= NEXP; ++e) a[e] += __shfl_down(a[e], off);
  }
  __shared__ float red[4][NEXP + 1];
  if ((t & 63) == 0) {
    #pragma unroll
    for (int e = 0; e <= NEXP; ++e) red[t >> 6][e] = a[e];
  }
  __syncthreads();
  if (t == 0) {
    float l[NEXP + 1];
    #pragma unroll
    for (int e = 0; e <= NEXP; ++e) l[e] = red[0][e] + red[1][e] + red[2][e] + red[3][e];
    int i1 = 0;
    #pragma unroll
    for (int e = 1; e < NEXP; ++e) if (l[e] > l[i1]) i1 = e;
    int i2 = (i1 == 0) ? 1 : 0;
    #pragma unroll
    for (int e = 0; e < NEXP; ++e) if (e != i1 && e != i2 && l[e] > l[i2]) i2 = e;
    const float w1 = 1.f / (1.f + __expf(l[i2] - l[i1]));   // softmax+top2+renorm == sigmoid(diff)
    tok_e[tkn * 2 + 0] = i1; tok_e[tkn * 2 + 1] = i2;
    tok_w[tkn * 2 + 0] = w1; tok_w[tkn * 2 + 1] = 1.f - w1;
    atomicAdd(&cnt[i1], 1); atomicAdd(&cnt[i2], 1);
    sg[tkn] = 1.f / (1.f + __expf(-l[NEXP]));
  }
}

__global__ void scan_kernel(const int* __restrict__ cnt, int* __restrict__ offs) {
  if (threadIdx.x == 0) {
    int r = 0;
    for (int e = 0; e < NEXP; ++e) { offs[e] = r; r += cnt[e]; }
  }
}

__global__ __launch_bounds__(256) void build_kernel(
    const int* __restrict__ tok_e, const float* __restrict__ tok_w,
    const int* __restrict__ offs, int* __restrict__ cur,
    int* __restrict__ list, float* __restrict__ wl)
{
  const int tkn = blockIdx.x * 256 + threadIdx.x;
  if (tkn >= TOK) return;
  #pragma unroll
  for (int k = 0; k < 2; ++k) {
    const int e = tok_e[tkn * 2 + k];
    const int pos = atomicAdd(&cur[e], 1);
    const int slot = offs[e] + pos;
    list[slot] = tkn;
    wl[slot] = tok_w[tkn * 2 + k];
  }
}

// ---------------- preprocessing ----------------
__global__ __launch_bounds__(256) void cvt_kernel(
    const float* __restrict__ src, unsigned short* __restrict__ dst, int n4)
{
  const int i = blockIdx.x * 512 + threadIdx.x;
  #pragma unroll
  for (int p = 0; p < 2; ++p) {
    const int j = i + p * 256;
    if (j < n4) {
      const float4 v = ((const float4*)src)[j];
      ushort4 b; b.x = f2b(v.x); b.y = f2b(v.y); b.z = f2b(v.z); b.w = f2b(v.w);
      ((ushort4*)dst)[j] = b;
    }
  }
}

// legacy single-matrix transpose (fallback path). f32 [R][C] -> bf16 [C][R].
__global__ __launch_bounds__(256) void transpose_cvt_kernel(
    const float* __restrict__ src, unsigned short* __restrict__ dst,
    const int R, const int C)
{
  __shared__ unsigned short tile[64][72];
  const size_t mat = (size_t)blockIdx.z * R * C;
  const int c0 = blockIdx.x * 64, r0 = blockIdx.y * 64;
  const int t = threadIdx.x;
  const int rr = t >> 4, cc = (t & 15) * 4;
  #pragma unroll
  for (int p = 0; p < 4; ++p) {
    const int r = rr + p * 16;
    const float4 v = *(const float4*)(src + mat + (size_t)(r0 + r) * C + c0 + cc);
    tile[cc + 0][r] = f2b(v.x);
    tile[cc + 1][r] = f2b(v.y);
    tile[cc + 2][r] = f2b(v.z);
    tile[cc + 3][r] = f2b(v.w);
  }
  __syncthreads();
  #pragma unroll
  for (int p = 0; p < 2; ++p) {
    const int id = p * 256 + t;
    const int c = id >> 3, q = id & 7;
    const uint4 v = *(const uint4*)&tile[c][q * 8];
    *(uint4*)(dst + mat + (size_t)(c0 + c) * R + r0 + q * 8) = v;
  }
}

// ---------------- transpose W1-W4 (gate/up weights) in one dispatch ----------------
// 16896 blocks: [0,2816) sw_gate->W1; [2816,5632) sw_up->W2;
// [5632,11264) w_gate->W3; [11264,16896) w_up->W4.
__global__ __launch_bounds__(256) void transpose_gu_kernel(
    const float* __restrict__ sw_gate, const float* __restrict__ sw_up,
    const float* __restrict__ w_gate,  const float* __restrict__ w_up,
    unsigned short* __restrict__ W1, unsigned short* __restrict__ W2,
    unsigned short* __restrict__ W3, unsigned short* __restrict__ W4)
{
  __shared__ unsigned short tile[64][72];
  int b = blockIdx.x;
  const float* src; unsigned short* dst;
  int srcC, dstLen, cx, ry;
  if (b < 2816)       { src = sw_gate; dst = W1; srcC = ISDIM; dstLen = HDIM; cx = b % 88; ry = b / 88; }
  else if (b < 5632)  { b -= 2816; src = sw_up; dst = W2; srcC = ISDIM; dstLen = HDIM; cx = b % 88; ry = b / 88; }
  else if (b < 11264) { b -= 5632; const int e = b / 704, r = b % 704;
                        src = w_gate + (size_t)e * HDIM * IDIM; dst = W3 + (size_t)e * IDIM * HDIM;
                        srcC = IDIM; dstLen = HDIM; cx = r % 22; ry = r / 22; }
  else                { b -= 11264; const int e = b / 704, r = b % 704;
                        src = w_up + (size_t)e * HDIM * IDIM; dst = W4 + (size_t)e * IDIM * HDIM;
                        srcC = IDIM; dstLen = HDIM; cx = r % 22; ry = r / 22; }

  const int c0 = cx * 64, r0 = ry * 64;
  const int t = threadIdx.x;
  const int rr = t >> 4, cc = (t & 15) * 4;
  #pragma unroll
  for (int p = 0; p < 4; ++p) {
    const int r = rr + p * 16;
    const float4 v = *(const float4*)(src + (size_t)(r0 + r) * srcC + c0 + cc);
    tile[cc + 0][r] = f2b(v.x);
    tile[cc + 1][r] = f2b(v.y);
    tile[cc + 2][r] = f2b(v.z);
    tile[cc + 3][r] = f2b(v.w);
  }
  __syncthreads();
  #pragma unroll
  for (int p = 0; p < 2; ++p) {
    const int id = p * 256 + t;
    const int ci = id >> 3, q = id & 7;
    *(uint4*)(dst + (size_t)(c0 + ci) * dstLen + r0 + q * 8) = *(const uint4*)&tile[ci][q * 8];
  }
}

// ---------------- FUSED gateup (+interleaved W5/W6 transposes when MODE=1) ----------------
// MODE 0: grid 1088, plain GEMM blocks (gidx = blockIdx).
// MODE 1: grid 5436; GEMM at blockIdx%5==0 (gidx=blockIdx/5 < 1088); other blocks
//   transpose two 64x64 tiles of sw_down->W5 / w_down->W6 (16KB LDS; co-resident
//   with 2x64KB GEMM blocks within 160KB/CU). XCD panel mapping preserved:
//   real b = 5*gidx and 5*(gidx+8k) = b mod 8 invariant per panel.
template<int MODE>
__global__ __launch_bounds__(512) void gateup_fused_kernel(
    const unsigned short* __restrict__ Xb,
    const unsigned short* __restrict__ Wshg, const unsigned short* __restrict__ Wshu,
    const unsigned short* __restrict__ Wexg, const unsigned short* __restrict__ Wexu,
    unsigned short* __restrict__ shb, unsigned short* __restrict__ hb,
    const int* __restrict__ list, const int* __restrict__ offs, const int* __restrict__ cnt,
    const float* __restrict__ swDown, const float* __restrict__ wDown,
    unsigned short* __restrict__ W5, unsigned short* __restrict__ W6)
{
  __shared__ char smem[65536];
  const int t = threadIdx.x;
  int gidx;

  if (MODE == 1) {
    const int b = blockIdx.x;
    if (b % 5 != 0) {
      // ---------- interleaved transpose block: two 64x64 tiles ----------
      const int tix = b - (b / 5 + 1);
      if (tix >= 4224) return;
      const int half = t >> 8;
      const int t2 = t & 255;
      int tid2 = tix * 2 + half;                 // 0..8447
      const float* src; unsigned short* dst; int R, cx, ry;
      if (tid2 < 2816) {                         // sw_down [IS][H] -> W5 [H][IS]
        src = swDown; dst = W5; R = ISDIM; cx = tid2 & 31; ry = tid2 >> 5;
      } else {                                   // w_down e:[I][H] -> W6 e:[H][I]
        tid2 -= 2816;
        const int e = tid2 / 704, rem = tid2 % 704;
        cx = rem & 31; ry = rem >> 5;
        src = wDown + (size_t)e * IDIM * HDIM;
        dst = W6 + (size_t)e * HDIM * IDIM;
        R = IDIM;
      }
      unsigned short (*tile)[72] = (unsigned short(*)[72])(smem + half * 16384);
      const int c0 = cx * 64, r0 = ry * 64;
      const int rr = t2 >> 4, cc = (t2 & 15) * 4;
      #pragma unroll
      for (int p = 0; p < 4; ++p) {
        const int r = rr + p * 16;
        const float4 v = *(const float4*)(src + (size_t)(r0 + r) * HDIM + c0 + cc);
        tile[cc + 0][r] = f2b(v.x);
        tile[cc + 1][r] = f2b(v.y);
        tile[cc + 2][r] = f2b(v.z);
        tile[cc + 3][r] = f2b(v.w);
      }
      __syncthreads();
      #pragma unroll
      for (int p = 0; p < 2; ++p) {
        const int id = p * 256 + t2;
        const int ci = id >> 3, q = id & 7;
        *(uint4*)(dst + (size_t)(c0 + ci) * R + r0 + q * 8) = *(const uint4*)&tile[ci][q * 8];
      }
      return;
    }
    gidx = b / 5;
  } else {
    gidx = blockIdx.x;
  }

  // ---------- GEMM blocks (r10 unchanged) ----------
  const int xcd = gidx & 7;
  const int local = gidx >> 3;
  const int c = xcd + 8 * (local >> 3);
  const int mt = local & 7;
  if (c >= 132) return;

  int rowbase, mcnt, n0, N, gather;
  const unsigned short *Wg, *Wu;
  unsigned short* Cout;
  if (c < 44) {
    N = ISDIM; n0 = c * 128; rowbase = mt * 256; mcnt = 256; gather = 0;
    Wg = Wshg; Wu = Wshu; Cout = shb;
  } else {
    const int cE = c - 44;
    const int e = cE / 11, n = cE % 11;
    mcnt = cnt[e] - mt * 256;
    if (mcnt <= 0) return;
    N = IDIM; n0 = n * 128; rowbase = offs[e] + mt * 256; gather = 1;
    Wg = Wexg + (size_t)e * IDIM * HDIM;
    Wu = Wexu + (size_t)e * IDIM * HDIM;
    Cout = hb;
  }

  const int wid = t >> 6, lane = t & 63;
  const int wm = wid >> 1, wn = wid & 1;
  const int lcol = lane & 15, lk = lane >> 4;

  f32x4 accg[4][4], accu[4][4];
  #pragma unroll
  for (int i = 0; i < 4; ++i)
    #pragma unroll
    for (int j = 0; j < 4; ++j) { accg[i][j] = {0.f,0.f,0.f,0.f}; accu[i][j] = {0.f,0.f,0.f,0.f}; }

  int arow[2], akoff[2];
  #pragma unroll
  for (int p = 0; p < 2; ++p) {
    const int s = p * 512 + t;
    const int m = s >> 2;
    akoff[p] = (((s & 3) ^ ((m >> 1) & 3)) << 3);
    arow[p] = gather ? list[rowbase + m] : (rowbase + m);   // list zero-padded (4608)
  }
  const int albase0 = (t & 448) * 16;
  const int albase1 = (512 + (t & 448)) * 16;
  const int bmrow = n0 + (t >> 2);
  const int bkoff = (((t & 3) ^ (((t >> 2) >> 1) & 3)) << 3);
  const int blbase = (t & 448) * 16;

#define STAGE_GU(BUF, K0) do {                                                    \
    async16(smem + (BUF) + albase0,        Xb + (size_t)arow[0] * HDIM + (K0) + akoff[0]); \
    async16(smem + (BUF) + albase1,        Xb + (size_t)arow[1] * HDIM + (K0) + akoff[1]); \
    async16(smem + (BUF) + 16384 + blbase, Wg + (size_t)bmrow * HDIM + (K0) + bkoff); \
    async16(smem + (BUF) + 24576 + blbase, Wu + (size_t)bmrow * HDIM + (K0) + bkoff); \
  } while (0)

#define COMPUTE_GU(BUF) do {                                                      \
    bf16x8 af[4], bg[4], bu[4];                                                   \
    _Pragma("unroll")                                                             \
    for (int fm = 0; fm < 4; ++fm) {                                              \
      const int m = wm * 64 + fm * 16 + lcol;                                     \
      af[fm] = *(const bf16x8*)(smem + (BUF) + m * 64 + (((lk ^ ((m >> 1) & 3)) & 3) << 4)); \
    }                                                                             \
    _Pragma("unroll")                                                             \
    for (int fn = 0; fn < 4; ++fn) {                                              \
      const int n = wn * 64 + fn * 16 + lcol;                                     \
      const int ra = n * 64 + (((lk ^ ((n >> 1) & 3)) & 3) << 4);                 \
      bg[fn] = *(const bf16x8*)(smem + (BUF) + 16384 + ra);                       \
      bu[fn] = *(const bf16x8*)(smem + (BUF) + 24576 + ra);                       \
    }                                                                             \
    _Pragma("unroll")                                                             \
    for (int fm = 0; fm < 4; ++fm)                                                \
      _Pragma("unroll")                                                           \
      for (int fn = 0; fn < 4; ++fn) {                                            \
        accg[fm][fn] = __builtin_amdgcn_mfma_f32_16x16x32_bf16(af[fm], bg[fn], accg[fm][fn], 0, 0, 0); \
        accu[fm][fn] = __builtin_amdgcn_mfma_f32_16x16x32_bf16(af[fm], bu[fn], accu[fm][fn], 0, 0, 0); \
      } } while (0)

  STAGE_GU(0, 0);
  for (int it = 0; it < 31; ++it) {
    STAGE_GU(32768, (2 * it + 1) * 32);
    VWAIT_BAR(4);
    COMPUTE_GU(0);
    VBAR();
    STAGE_GU(0, (2 * it + 2) * 32);
    VWAIT_BAR(4);
    COMPUTE_GU(32768);
    VBAR();
  }
  STAGE_GU(32768, 63 * 32);
  VWAIT_BAR(4);
  COMPUTE_GU(0);
  VBAR();
  VWAIT_BAR(0);
  COMPUTE_GU(32768);
#undef STAGE_GU
#undef COMPUTE_GU

  #pragma unroll
  for (int fm = 0; fm < 4; ++fm) {
    #pragma unroll
    for (int fn = 0; fn < 4; ++fn) {
      const int col = n0 + wn * 64 + fn * 16 + lcol;
      #pragma unroll
      for (int r = 0; r < 4; ++r) {
        const int lrow = wm * 64 + fm * 16 + lk * 4 + r;
        if (lrow < mcnt) {
          const float gv = accg[fm][fn][r];
          const float uv = accu[fm][fn][r];
          const float hv = gv * uv / (1.f + __expf(-gv));
          Cout[(size_t)(rowbase + lrow) * N + col] = f2b(hv);
        }
      }
    }
  }
}

// ---------------- FUSED down: r10 verbatim (256x128, 2-buffer 48KB, vmcnt(3)) ----------------
__global__ __launch_bounds__(512) void down_fused_kernel(
    const unsigned short* __restrict__ shb, const unsigned short* __restrict__ hb,
    const unsigned short* __restrict__ WdshT, const unsigned short* __restrict__ WdexT,
    float* __restrict__ out,
    const int* __restrict__ list, const float* __restrict__ wl, const float* __restrict__ sg,
    const int* __restrict__ offs, const int* __restrict__ cnt)
{
  __shared__ char smem[49152];

  const int xcd = blockIdx.x & 7;
  const int local = blockIdx.x >> 3;
  const int c = xcd + 8 * (local >> 3);   // 0..191
  const int mt = local & 7;
  const int t = threadIdx.x;

  int rowbase, mcnt, n0, K, kbeg, em;
  const unsigned short *Ap, *Bp;
  if (c < 64) {                // shared, splitK=4 (44 steps each)
    const int pn = c & 15, ksp = c >> 4;
    rowbase = mt * 256; mcnt = 256; n0 = pn * 128;
    K = ISDIM; kbeg = ksp * 44; em = 0;
    Ap = shb; Bp = WdshT;
  } else {                     // expert (44 steps)
    const int cE = c - 64;
    const int e = cE >> 4, n = cE & 15;
    mcnt = cnt[e] - mt * 256;
    if (mcnt <= 0) return;
    rowbase = offs[e] + mt * 256; n0 = n * 128;
    K = IDIM; kbeg = 0; em = 1;
    Ap = hb; Bp = WdexT + (size_t)e * HDIM * IDIM;
  }

  const int wid = t >> 6, lane = t & 63;
  const int wm = wid >> 1, wn = wid & 1;
  const int lcol = lane & 15, lk = lane >> 4;

  f32x4 acc[4][4];
  #pragma unroll
  for (int i = 0; i < 4; ++i)
    #pragma unroll
    for (int j = 0; j < 4; ++j) acc[i][j] = {0.f,0.f,0.f,0.f};

  int amrow[2], akoff[2];
  #pragma unroll
  for (int p = 0; p < 2; ++p) {
    const int s = p * 512 + t;
    const int m = s >> 2;
    akoff[p] = (((s & 3) ^ ((m >> 1) & 3)) << 3);
    int rw = rowbase + m;
    if (em && rw > 4223) rw = 4223;    // clamp: hb has 4224 row slots
    amrow[p] = rw;
  }
  const int albase0 = (t & 448) * 16;
  const int albase1 = (512 + (t & 448)) * 16;
  const int bmrow = n0 + (t >> 2);
  const int bkoff = (((t & 3) ^ (((t >> 2) >> 1) & 3)) << 3);
  const int blbase = (t & 448) * 16;

#define STAGE_D(BUF, K0) do {                                                     \
    async16(smem + (BUF) + albase0,        Ap + (size_t)amrow[0] * K + (K0) + akoff[0]); \
    async16(smem + (BUF) + albase1,        Ap + (size_t)amrow[1] * K + (K0) + akoff[1]); \
    async16(smem + (BUF) + 16384 + blbase, Bp + (size_t)bmrow * K + (K0) + bkoff); \
  } while (0)

#define COMPUTE_D(BUF) do {                                                       \
    bf16x8 af[4], bfr[4];                                                         \
    _Pragma("unroll")                                                             \
    for (int fm = 0; fm < 4; ++fm) {                                              \
      const int m = wm * 64 + fm * 16 + lcol;                                     \
      af[fm] = *(const bf16x8*)(smem + (BUF) + m * 64 + (((lk ^ ((m >> 1) & 3)) & 3) << 4)); \
    }                                                                             \
    _Pragma("unroll")                                                             \
    for (int fn = 0; fn < 4; ++fn) {                                              \
      const int n = wn * 64 + fn * 16 + lcol;                                     \
      bfr[fn] = *(const bf16x8*)(smem + (BUF) + 16384 + n * 64 + (((lk ^ ((n >> 1) & 3)) & 3) << 4)); \
    }                                                                             \
    _Pragma("unroll")                                                             \
    for (int fm = 0; fm < 4; ++fm)                                                \
      _Pragma("unroll")                                                           \
      for (int fn = 0; fn < 4; ++fn)                                              \
        acc[fm][fn] = __builtin_amdgcn_mfma_f32_16x16x32_bf16(af[fm], bfr[fn], acc[fm][fn], 0, 0, 0); \
  } while (0)

  const int kb = kbeg * 32;
  STAGE_D(0, kb);
  for (int it = 0; it < 21; ++it) {
    STAGE_D(24576, kb + (2 * it + 1) * 32);
    VWAIT_BAR(3);
    COMPUTE_D(0);
    VBAR();
    STAGE_D(0, kb + (2 * it + 2) * 32);
    VWAIT_BAR(3);
    COMPUTE_D(24576);
    VBAR();
  }
  STAGE_D(24576, kb + 43 * 32);
  VWAIT_BAR(3);
  COMPUTE_D(0);
  VBAR();
  VWAIT_BAR(0);
  COMPUTE_D(24576);
#undef STAGE_D
#undef COMPUTE_D

  #pragma unroll
  for (int fm = 0; fm < 4; ++fm) {
    #pragma unroll
    for (int fn = 0; fn < 4; ++fn) {
      const int col = n0 + wn * 64 + fn * 16 + lcol;
      #pragma unroll
      for (int r = 0; r < 4; ++r) {
        const int lrow = wm * 64 + fm * 16 + lk * 4 + r;
        if (lrow < mcnt) {
          const float v = acc[fm][fn][r];
          const int sl = rowbase + lrow;
          const int orow = em ? list[sl] : sl;
          const float sc = em ? wl[sl] : sg[sl];
          atomicAdd(out + (size_t)orow * HDIM + col, sc * v);
        }
      }
    }
  }
}

extern "C" void kernel_launch(void* const* d_in, const int* in_sizes, int n_in,
                              void* d_out, int out_size, void* d_ws, size_t ws_size,
                              hipStream_t stream)
{
  const float* x       = (const float*)d_in[0];
  const float* gate_w  = (const float*)d_in[1];
  const float* w_gate  = (const float*)d_in[2];
  const float* w_up    = (const float*)d_in[3];
  const float* w_down  = (const float*)d_in[4];
  const float* sw_gate = (const float*)d_in[5];
  const float* sw_up   = (const float*)d_in[6];
  const float* sw_down = (const float*)d_in[7];
  const float* sgw     = (const float*)d_in[8];

  float* out = (float*)d_out;   // f32 [TOK][H]; pure accumulator (zeroed)
  char* ws = (char*)d_ws;

  const size_t NEED_OVL   = 251100000;   // all-weights layout (~251 MB)
  const size_t NEED_FUSED = 182000000;   // r10 layout

  if (ws_size >= NEED_OVL) {
    unsigned short* Xb  = (unsigned short*)ws;                      //   8,388,608
    unsigned short* W1  = (unsigned short*)(ws + 8388608);          //  23,068,672 shG^T
    unsigned short* W2  = (unsigned short*)(ws + 31457280);         //  23,068,672 shU^T
    unsigned short* W3  = (unsigned short*)(ws + 54525952);         //  46,137,344 exG^T
    unsigned short* W4  = (unsigned short*)(ws + 100663296);        //  46,137,344 exU^T
    unsigned short* W5  = (unsigned short*)(ws + 146800640);        //  23,068,672 shDown^T
    unsigned short* W6  = (unsigned short*)(ws + 169869312);        //  46,137,344 exDown^T
    unsigned short* shb = (unsigned short*)(ws + 216006656);        //  23,068,672
    unsigned short* hb  = (unsigned short*)(ws + 239075328);        //  11,894,784
    char* meta = ws + 250970112;
    int*   cnt   = (int*)(meta);
    int*   cur   = (int*)(meta + 256);
    int*   offs  = (int*)(meta + 512);
    int*   list  = (int*)(meta + 768);                 // 4608 ints (zero-padded)
    float* wl    = (float*)(meta + 768 + 18432);       // 4608 floats (zero-padded)
    int*   tok_e = (int*)(meta + 768 + 2 * 18432);
    float* tok_w = (float*)(meta + 768 + 2 * 18432 + 16384);
    float* sg    = (float*)(meta + 768 + 2 * 18432 + 32768);

    hipMemsetAsync(meta, 0, 768 + 2 * 18432, stream);
    hipMemsetAsync(out, 0, (size_t)TOK * HDIM * 4, stream);

    cvt_kernel<<<TOK * HDIM / 4 / 512, 256, 0, stream>>>(x, Xb, TOK * HDIM / 4);
    router_kernel<<<TOK, 256, 0, stream>>>(x, gate_w, sgw, cnt, tok_e, tok_w, sg);
    scan_kernel<<<1, 64, 0, stream>>>(cnt, offs);
    build_kernel<<<8, 256, 0, stream>>>(tok_e, tok_w, offs, cur, list, wl);

    // serial transpose: only W1-W4 (gateup inputs)
    transpose_gu_kernel<<<16896, 256, 0, stream>>>(
        sw_gate, sw_up, w_gate, w_up, W1, W2, W3, W4);

    // gateup GEMM (stride-5 indices) + interleaved W5/W6 transpose blocks
    gateup_fused_kernel<1><<<5436, 512, 0, stream>>>(
        Xb, W1, W2, W3, W4, shb, hb, list, offs, cnt, sw_down, w_down, W5, W6);

    down_fused_kernel<<<1536, 512, 0, stream>>>(shb, hb, W5, W6, out, list, wl, sg, offs, cnt);
  } else if (ws_size >= NEED_FUSED) {
    // r10 layout: down-weight transposes overwrite W1/W3 after gateup
    unsigned short* Xb  = (unsigned short*)ws;
    unsigned short* W1  = (unsigned short*)(ws + 8388608);
    unsigned short* W2  = (unsigned short*)(ws + 31457280);
    unsigned short* W3  = (unsigned short*)(ws + 54525952);
    unsigned short* W4  = (unsigned short*)(ws + 100663296);
    unsigned short* shb = (unsigned short*)(ws + 146800640);
    unsigned short* hb  = (unsigned short*)(ws + 169869312);
    char* meta = ws + 181764096;
    int*   cnt   = (int*)(meta);
    int*   cur   = (int*)(meta + 256);
    int*   offs  = (int*)(meta + 512);
    int*   list  = (int*)(meta + 768);
    float* wl    = (float*)(meta + 768 + 18432);
    int*   tok_e = (int*)(meta + 768 + 2 * 18432);
    float* tok_w = (float*)(meta + 768 + 2 * 18432 + 16384);
    float* sg    = (float*)(meta + 768 + 2 * 18432 + 32768);

    hipMemsetAsync(meta, 0, 768 + 2 * 18432, stream);
    hipMemsetAsync(out, 0, (size_t)TOK * HDIM * 4, stream);

    cvt_kernel<<<TOK * HDIM / 4 / 512, 256, 0, stream>>>(x, Xb, TOK * HDIM / 4);
    router_kernel<<<TOK, 256, 0, stream>>>(x, gate_w, sgw, cnt, tok_e, tok_w, sg);
    scan_kernel<<<1, 64, 0, stream>>>(cnt, offs);
    build_kernel<<<8, 256, 0, stream>>>(tok_e, tok_w, offs, cur, list, wl);

    transpose_cvt_kernel<<<dim3(ISDIM / 64, HDIM / 64, 1), 256, 0, stream>>>(sw_gate, W1, HDIM, ISDIM);
    transpose_cvt_kernel<<<dim3(ISDIM / 64, HDIM / 64, 1), 256, 0, stream>>>(sw_up,   W2, HDIM, ISDIM);
    transpose_cvt_kernel<<<dim3(IDIM / 64, HDIM / 64, NEXP), 256, 0, stream>>>(w_gate, W3, HDIM, IDIM);
    transpose_cvt_kernel<<<dim3(IDIM / 64, HDIM / 64, NEXP), 256, 0, stream>>>(w_up,   W4, HDIM, IDIM);

    gateup_fused_kernel<0><<<1088, 512, 0, stream>>>(
        Xb, W1, W2, W3, W4, shb, hb, list, offs, cnt, nullptr, nullptr, nullptr, nullptr);

    transpose_cvt_kernel<<<dim3(HDIM / 64, ISDIM / 64, 1), 256, 0, stream>>>(sw_down, W1, ISDIM, HDIM);
    transpose_cvt_kernel<<<dim3(HDIM / 64, IDIM / 64, NEXP), 256, 0, stream>>>(w_down, W3, IDIM, HDIM);

    down_fused_kernel<<<1536, 512, 0, stream>>>(shb, hb, W1, W3, out, list, wl, sg, offs, cnt);
  }
}

// Round 16
// 572.243 us; speedup vs baseline: 1.0534x; 1.0534x over previous
//
#include <hip/hip_runtime.h>
#include <hip/hip_bf16.h>
#include <stdint.h>

// Qwen3.5 MoE block: router top-2 sparse dispatch + shared expert (SwiGLU), bf16 MFMA.
// B=2,S=1024 -> TOK=2048 tokens. H=2048, I=1408, IS=5632, E=8, K=2. Output f32.
// Round 16: consolidation of measured-best components. GEMMs = round-10 exact
// (gateup 256x128 counted-vmcnt dbuf; down 256x128 2-buffer 48KB vmcnt(3)).
// ONE preprocessing dispatch = six weight transposes + X cvt + router (all
// independent; router VALU work hides under the HBM-bound transpose).
#define TOK   2048
#define HDIM  2048
#define IDIM  1408
#define ISDIM 5632
#define NEXP  8

typedef float  f32x4  __attribute__((ext_vector_type(4)));
typedef short  bf16x8 __attribute__((ext_vector_type(8)));

__device__ __forceinline__ unsigned short f2b(float f) {
  union { float f; uint32_t u; } v; v.f = f;
  return (unsigned short)((v.u + 0x7fffu + ((v.u >> 16) & 1u)) >> 16); // RNE
}

// async global->LDS DMA, 16 B per lane: LDS dest wave-uniform base + lane*16.
__device__ __forceinline__ void async16(void* lds, const void* g) {
  __builtin_amdgcn_global_load_lds(
      (const __attribute__((address_space(1))) unsigned int*)g,
      (__attribute__((address_space(3))) unsigned int*)lds, 16, 0, 0);
}

// counted-vmcnt + raw barrier (no lgkm/vm drain); "memory" clobber pins LDS/VMEM ops.
#define VWAIT_BAR(N) asm volatile("s_waitcnt vmcnt(" #N ")\n\ts_barrier" ::: "memory")
#define VBAR()       asm volatile("s_barrier" ::: "memory")

// ---------------- router (standalone, for fallback path) ----------------
__global__ __launch_bounds__(256) void router_kernel(
    const float* __restrict__ X, const float* __restrict__ GW,
    const float* __restrict__ SGW, int* __restrict__ cnt,
    int* __restrict__ tok_e, float* __restrict__ tok_w, float* __restrict__ sg)
{
  const int tkn = blockIdx.x, t = threadIdx.x;
  const float* xr = X + (size_t)tkn * HDIM;
  float a[NEXP + 1];
  #pragma unroll
  for (int e = 0; e <= NEXP; ++e) a[e] = 0.f;
  for (int h = t; h < HDIM; h += 256) {
    const float xv = xr[h];
    #pragma unroll
    for (int e = 0; e < NEXP; ++e) a[e] += xv * GW[e * HDIM + h];
    a[NEXP] += xv * SGW[h];
  }
  #pragma unroll
  for (int off = 32; off > 0; off >>= 1) {
    #pragma unroll
    for (int e = 0; e <= NEXP; ++e) a[e] += __shfl_down(a[e], off);
  }
  __shared__ float red[4][NEXP + 1];
  if ((t & 63) == 0) {
    #pragma unroll
    for (int e = 0; e <= NEXP; ++e) red[t >> 6][e] = a[e];
  }
  __syncthreads();
  if (t == 0) {
    float l[NEXP + 1];
    #pragma unroll
    for (int e = 0; e <= NEXP; ++e) l[e] = red[0][e] + red[1][e] + red[2][e] + red[3][e];
    int i1 = 0;
    #pragma unroll
    for (int e = 1; e < NEXP; ++e) if (l[e] > l[i1]) i1 = e;
    int i2 = (i1 == 0) ? 1 : 0;
    #pragma unroll
    for (int e = 0; e < NEXP; ++e) if (e != i1 && e != i2 && l[e] > l[i2]) i2 = e;
    const float w1 = 1.f / (1.f + __expf(l[i2] - l[i1]));   // softmax+top2+renorm == sigmoid(diff)
    tok_e[tkn * 2 + 0] = i1; tok_e[tkn * 2 + 1] = i2;
    tok_w[tkn * 2 + 0] = w1; tok_w[tkn * 2 + 1] = 1.f - w1;
    atomicAdd(&cnt[i1], 1); atomicAdd(&cnt[i2], 1);
    sg[tkn] = 1.f / (1.f + __expf(-l[NEXP]));
  }
}

__global__ void scan_kernel(const int* __restrict__ cnt, int* __restrict__ offs) {
  if (threadIdx.x == 0) {
    int r = 0;
    for (int e = 0; e < NEXP; ++e) { offs[e] = r; r += cnt[e]; }
  }
}

__global__ __launch_bounds__(256) void build_kernel(
    const int* __restrict__ tok_e, const float* __restrict__ tok_w,
    const int* __restrict__ offs, int* __restrict__ cur,
    int* __restrict__ list, float* __restrict__ wl)
{
  const int tkn = blockIdx.x * 256 + threadIdx.x;
  if (tkn >= TOK) return;
  #pragma unroll
  for (int k = 0; k < 2; ++k) {
    const int e = tok_e[tkn * 2 + k];
    const int pos = atomicAdd(&cur[e], 1);
    const int slot = offs[e] + pos;
    list[slot] = tkn;
    wl[slot] = tok_w[tkn * 2 + k];
  }
}

// ---------------- preprocessing (standalone, for fallback path) ----------------
__global__ __launch_bounds__(256) void cvt_kernel(
    const float* __restrict__ src, unsigned short* __restrict__ dst, int n4)
{
  const int i = blockIdx.x * 512 + threadIdx.x;
  #pragma unroll
  for (int p = 0; p < 2; ++p) {
    const int j = i + p * 256;
    if (j < n4) {
      const float4 v = ((const float4*)src)[j];
      ushort4 b; b.x = f2b(v.x); b.y = f2b(v.y); b.z = f2b(v.z); b.w = f2b(v.w);
      ((ushort4*)dst)[j] = b;
    }
  }
}

// legacy single-matrix transpose (fallback path). f32 [R][C] -> bf16 [C][R].
__global__ __launch_bounds__(256) void transpose_cvt_kernel(
    const float* __restrict__ src, unsigned short* __restrict__ dst,
    const int R, const int C)
{
  __shared__ unsigned short tile[64][72];
  const size_t mat = (size_t)blockIdx.z * R * C;
  const int c0 = blockIdx.x * 64, r0 = blockIdx.y * 64;
  const int t = threadIdx.x;
  const int rr = t >> 4, cc = (t & 15) * 4;
  #pragma unroll
  for (int p = 0; p < 4; ++p) {
    const int r = rr + p * 16;
    const float4 v = *(const float4*)(src + mat + (size_t)(r0 + r) * C + c0 + cc);
    tile[cc + 0][r] = f2b(v.x);
    tile[cc + 1][r] = f2b(v.y);
    tile[cc + 2][r] = f2b(v.z);
    tile[cc + 3][r] = f2b(v.w);
  }
  __syncthreads();
  #pragma unroll
  for (int p = 0; p < 2; ++p) {
    const int id = p * 256 + t;
    const int c = id >> 3, q = id & 7;
    const uint4 v = *(const uint4*)&tile[c][q * 8];
    *(uint4*)(dst + mat + (size_t)(c0 + c) * R + r0 + q * 8) = v;
  }
}

// ---------------- unified preprocessing: 6 transposes + X cvt + router ----------------
// blocks [0,25344): weight transposes (64x64 tiles, descriptor ranges)
// blocks [25344,26368): X f32->bf16 cvt (1024 blocks x 1024 float4)
// blocks [26368,28416): router (2048 blocks, one token each)
__global__ __launch_bounds__(256) void prep_all_kernel(
    const float* __restrict__ Xf,
    const float* __restrict__ gate_w, const float* __restrict__ sgw,
    const float* __restrict__ sw_gate, const float* __restrict__ sw_up,
    const float* __restrict__ w_gate,  const float* __restrict__ w_up,
    const float* __restrict__ sw_down, const float* __restrict__ w_down,
    unsigned short* __restrict__ W1, unsigned short* __restrict__ W2,
    unsigned short* __restrict__ W3, unsigned short* __restrict__ W4,
    unsigned short* __restrict__ W5, unsigned short* __restrict__ W6,
    unsigned short* __restrict__ Xb,
    int* __restrict__ cnt, int* __restrict__ tok_e,
    float* __restrict__ tok_w, float* __restrict__ sg)
{
  const int t = threadIdx.x;

  if (blockIdx.x >= 26368) {
    // ---------- router ----------
    const int tkn = blockIdx.x - 26368;
    const float* xr = Xf + (size_t)tkn * HDIM;
    float a[NEXP + 1];
    #pragma unroll
    for (int e = 0; e <= NEXP; ++e) a[e] = 0.f;
    for (int h = t; h < HDIM; h += 256) {
      const float xv = xr[h];
      #pragma unroll
      for (int e = 0; e < NEXP; ++e) a[e] += xv * gate_w[e * HDIM + h];
      a[NEXP] += xv * sgw[h];
    }
    #pragma unroll
    for (int off = 32; off > 0; off >>= 1) {
      #pragma unroll
      for (int e = 0; e <= NEXP; ++e) a[e] += __shfl_down(a[e], off);
    }
    __shared__ float red[4][NEXP + 1];
    if ((t & 63) == 0) {
      #pragma unroll
      for (int e = 0; e <= NEXP; ++e) red[t >> 6][e] = a[e];
    }
    __syncthreads();
    if (t == 0) {
      float l[NEXP + 1];
      #pragma unroll
      for (int e = 0; e <= NEXP; ++e) l[e] = red[0][e] + red[1][e] + red[2][e] + red[3][e];
      int i1 = 0;
      #pragma unroll
      for (int e = 1; e < NEXP; ++e) if (l[e] > l[i1]) i1 = e;
      int i2 = (i1 == 0) ? 1 : 0;
      #pragma unroll
      for (int e = 0; e < NEXP; ++e) if (e != i1 && e != i2 && l[e] > l[i2]) i2 = e;
      const float w1 = 1.f / (1.f + __expf(l[i2] - l[i1]));
      tok_e[tkn * 2 + 0] = i1; tok_e[tkn * 2 + 1] = i2;
      tok_w[tkn * 2 + 0] = w1; tok_w[tkn * 2 + 1] = 1.f - w1;
      atomicAdd(&cnt[i1], 1); atomicAdd(&cnt[i2], 1);
      sg[tkn] = 1.f / (1.f + __expf(-l[NEXP]));
    }
    return;
  }

  if (blockIdx.x >= 25344) {
    // ---------- X cvt: 1024 blocks x (256 thr x 4 float4) ----------
    const int gi = (blockIdx.x - 25344) * 256 + t;
    #pragma unroll
    for (int p = 0; p < 4; ++p) {
      const int j = gi + p * 262144;           // 1,048,576 float4 total
      const float4 v = ((const float4*)Xf)[j];
      ushort4 b; b.x = f2b(v.x); b.y = f2b(v.y); b.z = f2b(v.z); b.w = f2b(v.w);
      ((ushort4*)Xb)[j] = b;
    }
    return;
  }

  // ---------- weight transposes (r14-verified descriptor math) ----------
  __shared__ unsigned short tile[64][72];
  int b = blockIdx.x;
  const float* src; unsigned short* dst;
  int srcC, dstLen, cx, ry;
  if (b < 2816)       { src = sw_gate; dst = W1; srcC = ISDIM; dstLen = HDIM; cx = b % 88; ry = b / 88; }
  else if (b < 5632)  { b -= 2816; src = sw_up; dst = W2; srcC = ISDIM; dstLen = HDIM; cx = b % 88; ry = b / 88; }
  else if (b < 11264) { b -= 5632; const int e = b / 704, r = b % 704;
                        src = w_gate + (size_t)e * HDIM * IDIM; dst = W3 + (size_t)e * IDIM * HDIM;
                        srcC = IDIM; dstLen = HDIM; cx = r % 22; ry = r / 22; }
  else if (b < 16896) { b -= 11264; const int e = b / 704, r = b % 704;
                        src = w_up + (size_t)e * HDIM * IDIM; dst = W4 + (size_t)e * IDIM * HDIM;
                        srcC = IDIM; dstLen = HDIM; cx = r % 22; ry = r / 22; }
  else if (b < 19712) { b -= 16896; src = sw_down; dst = W5; srcC = HDIM; dstLen = ISDIM; cx = b % 32; ry = b / 32; }
  else                { b -= 19712; const int e = b / 704, r = b % 704;
                        src = w_down + (size_t)e * IDIM * HDIM; dst = W6 + (size_t)e * HDIM * IDIM;
                        srcC = HDIM; dstLen = IDIM; cx = r % 32; ry = r / 32; }

  const int c0 = cx * 64, r0 = ry * 64;
  const int rr = t >> 4, cc = (t & 15) * 4;
  #pragma unroll
  for (int p = 0; p < 4; ++p) {
    const int r = rr + p * 16;
    const float4 v = *(const float4*)(src + (size_t)(r0 + r) * srcC + c0 + cc);
    tile[cc + 0][r] = f2b(v.x);
    tile[cc + 1][r] = f2b(v.y);
    tile[cc + 2][r] = f2b(v.z);
    tile[cc + 3][r] = f2b(v.w);
  }
  __syncthreads();
  #pragma unroll
  for (int p = 0; p < 2; ++p) {
    const int id = p * 256 + t;
    const int ci = id >> 3, q = id & 7;
    *(uint4*)(dst + (size_t)(c0 + ci) * dstLen + r0 + q * 8) = *(const uint4*)&tile[ci][q * 8];
  }
}

// ---------------- FUSED gateup: 256x128 tile, 8 waves, BK=32, counted-vmcnt dbuf (r10) ----------------
__global__ __launch_bounds__(512) void gateup_fused_kernel(
    const unsigned short* __restrict__ Xb,
    const unsigned short* __restrict__ Wshg, const unsigned short* __restrict__ Wshu,
    const unsigned short* __restrict__ Wexg, const unsigned short* __restrict__ Wexu,
    unsigned short* __restrict__ shb, unsigned short* __restrict__ hb,
    const int* __restrict__ list, const int* __restrict__ offs, const int* __restrict__ cnt)
{
  __shared__ char smem[65536];

  const int xcd = blockIdx.x & 7;
  const int local = blockIdx.x >> 3;
  const int c = xcd + 8 * (local >> 3);
  const int mt = local & 7;
  if (c >= 132) return;
  const int t = threadIdx.x;

  int rowbase, mcnt, n0, N, gather;
  const unsigned short *Wg, *Wu;
  unsigned short* Cout;
  if (c < 44) {
    N = ISDIM; n0 = c * 128; rowbase = mt * 256; mcnt = 256; gather = 0;
    Wg = Wshg; Wu = Wshu; Cout = shb;
  } else {
    const int cE = c - 44;
    const int e = cE / 11, n = cE % 11;
    mcnt = cnt[e] - mt * 256;
    if (mcnt <= 0) return;
    N = IDIM; n0 = n * 128; rowbase = offs[e] + mt * 256; gather = 1;
    Wg = Wexg + (size_t)e * IDIM * HDIM;
    Wu = Wexu + (size_t)e * IDIM * HDIM;
    Cout = hb;
  }

  const int wid = t >> 6, lane = t & 63;
  const int wm = wid >> 1, wn = wid & 1;
  const int lcol = lane & 15, lk = lane >> 4;

  f32x4 accg[4][4], accu[4][4];
  #pragma unroll
  for (int i = 0; i < 4; ++i)
    #pragma unroll
    for (int j = 0; j < 4; ++j) { accg[i][j] = {0.f,0.f,0.f,0.f}; accu[i][j] = {0.f,0.f,0.f,0.f}; }

  int arow[2], akoff[2];
  #pragma unroll
  for (int p = 0; p < 2; ++p) {
    const int s = p * 512 + t;
    const int m = s >> 2;
    akoff[p] = (((s & 3) ^ ((m >> 1) & 3)) << 3);
    arow[p] = gather ? list[rowbase + m] : (rowbase + m);   // list zero-padded (4608)
  }
  const int albase0 = (t & 448) * 16;
  const int albase1 = (512 + (t & 448)) * 16;
  const int bmrow = n0 + (t >> 2);
  const int bkoff = (((t & 3) ^ (((t >> 2) >> 1) & 3)) << 3);
  const int blbase = (t & 448) * 16;

#define STAGE_GU(BUF, K0) do {                                                    \
    async16(smem + (BUF) + albase0,        Xb + (size_t)arow[0] * HDIM + (K0) + akoff[0]); \
    async16(smem + (BUF) + albase1,        Xb + (size_t)arow[1] * HDIM + (K0) + akoff[1]); \
    async16(smem + (BUF) + 16384 + blbase, Wg + (size_t)bmrow * HDIM + (K0) + bkoff); \
    async16(smem + (BUF) + 24576 + blbase, Wu + (size_t)bmrow * HDIM + (K0) + bkoff); \
  } while (0)

#define COMPUTE_GU(BUF) do {                                                      \
    bf16x8 af[4], bg[4], bu[4];                                                   \
    _Pragma("unroll")                                                             \
    for (int fm = 0; fm < 4; ++fm) {                                              \
      const int m = wm * 64 + fm * 16 + lcol;                                     \
      af[fm] = *(const bf16x8*)(smem + (BUF) + m * 64 + (((lk ^ ((m >> 1) & 3)) & 3) << 4)); \
    }                                                                             \
    _Pragma("unroll")                                                             \
    for (int fn = 0; fn < 4; ++fn) {                                              \
      const int n = wn * 64 + fn * 16 + lcol;                                     \
      const int ra = n * 64 + (((lk ^ ((n >> 1) & 3)) & 3) << 4);                 \
      bg[fn] = *(const bf16x8*)(smem + (BUF) + 16384 + ra);                       \
      bu[fn] = *(const bf16x8*)(smem + (BUF) + 24576 + ra);                       \
    }                                                                             \
    _Pragma("unroll")                                                             \
    for (int fm = 0; fm < 4; ++fm)                                                \
      _Pragma("unroll")                                                           \
      for (int fn = 0; fn < 4; ++fn) {                                            \
        accg[fm][fn] = __builtin_amdgcn_mfma_f32_16x16x32_bf16(af[fm], bg[fn], accg[fm][fn], 0, 0, 0); \
        accu[fm][fn] = __builtin_amdgcn_mfma_f32_16x16x32_bf16(af[fm], bu[fn], accu[fm][fn], 0, 0, 0); \
      } } while (0)

  STAGE_GU(0, 0);
  for (int it = 0; it < 31; ++it) {
    STAGE_GU(32768, (2 * it + 1) * 32);
    VWAIT_BAR(4);
    COMPUTE_GU(0);
    VBAR();
    STAGE_GU(0, (2 * it + 2) * 32);
    VWAIT_BAR(4);
    COMPUTE_GU(32768);
    VBAR();
  }
  STAGE_GU(32768, 63 * 32);
  VWAIT_BAR(4);
  COMPUTE_GU(0);
  VBAR();
  VWAIT_BAR(0);
  COMPUTE_GU(32768);
#undef STAGE_GU
#undef COMPUTE_GU

  #pragma unroll
  for (int fm = 0; fm < 4; ++fm) {
    #pragma unroll
    for (int fn = 0; fn < 4; ++fn) {
      const int col = n0 + wn * 64 + fn * 16 + lcol;
      #pragma unroll
      for (int r = 0; r < 4; ++r) {
        const int lrow = wm * 64 + fm * 16 + lk * 4 + r;
        if (lrow < mcnt) {
          const float gv = accg[fm][fn][r];
          const float uv = accu[fm][fn][r];
          const float hv = gv * uv / (1.f + __expf(-gv));
          Cout[(size_t)(rowbase + lrow) * N + col] = f2b(hv);
        }
      }
    }
  }
}

// ---------------- FUSED down: r10 verbatim (256x128, 2-buffer 48KB, vmcnt(3)) ----------------
__global__ __launch_bounds__(512) void down_fused_kernel(
    const unsigned short* __restrict__ shb, const unsigned short* __restrict__ hb,
    const unsigned short* __restrict__ WdshT, const unsigned short* __restrict__ WdexT,
    float* __restrict__ out,
    const int* __restrict__ list, const float* __restrict__ wl, const float* __restrict__ sg,
    const int* __restrict__ offs, const int* __restrict__ cnt)
{
  __shared__ char smem[49152];

  const int xcd = blockIdx.x & 7;
  const int local = blockIdx.x >> 3;
  const int c = xcd + 8 * (local >> 3);   // 0..191
  const int mt = local & 7;
  const int t = threadIdx.x;

  int rowbase, mcnt, n0, K, kbeg, em;
  const unsigned short *Ap, *Bp;
  if (c < 64) {                // shared, splitK=4 (44 steps each)
    const int pn = c & 15, ksp = c >> 4;
    rowbase = mt * 256; mcnt = 256; n0 = pn * 128;
    K = ISDIM; kbeg = ksp * 44; em = 0;
    Ap = shb; Bp = WdshT;
  } else {                     // expert (44 steps)
    const int cE = c - 64;
    const int e = cE >> 4, n = cE & 15;
    mcnt = cnt[e] - mt * 256;
    if (mcnt <= 0) return;
    rowbase = offs[e] + mt * 256; n0 = n * 128;
    K = IDIM; kbeg = 0; em = 1;
    Ap = hb; Bp = WdexT + (size_t)e * HDIM * IDIM;
  }

  const int wid = t >> 6, lane = t & 63;
  const int wm = wid >> 1, wn = wid & 1;
  const int lcol = lane & 15, lk = lane >> 4;

  f32x4 acc[4][4];
  #pragma unroll
  for (int i = 0; i < 4; ++i)
    #pragma unroll
    for (int j = 0; j < 4; ++j) acc[i][j] = {0.f,0.f,0.f,0.f};

  int amrow[2], akoff[2];
  #pragma unroll
  for (int p = 0; p < 2; ++p) {
    const int s = p * 512 + t;
    const int m = s >> 2;
    akoff[p] = (((s & 3) ^ ((m >> 1) & 3)) << 3);
    int rw = rowbase + m;
    if (em && rw > 4223) rw = 4223;    // clamp: hb has 4224 row slots
    amrow[p] = rw;
  }
  const int albase0 = (t & 448) * 16;
  const int albase1 = (512 + (t & 448)) * 16;
  const int bmrow = n0 + (t >> 2);
  const int bkoff = (((t & 3) ^ (((t >> 2) >> 1) & 3)) << 3);
  const int blbase = (t & 448) * 16;

#define STAGE_D(BUF, K0) do {                                                     \
    async16(smem + (BUF) + albase0,        Ap + (size_t)amrow[0] * K + (K0) + akoff[0]); \
    async16(smem + (BUF) + albase1,        Ap + (size_t)amrow[1] * K + (K0) + akoff[1]); \
    async16(smem + (BUF) + 16384 + blbase, Bp + (size_t)bmrow * K + (K0) + bkoff); \
  } while (0)

#define COMPUTE_D(BUF) do {                                                       \
    bf16x8 af[4], bfr[4];                                                         \
    _Pragma("unroll")                                                             \
    for (int fm = 0; fm < 4; ++fm) {                                              \
      const int m = wm * 64 + fm * 16 + lcol;                                     \
      af[fm] = *(const bf16x8*)(smem + (BUF) + m * 64 + (((lk ^ ((m >> 1) & 3)) & 3) << 4)); \
    }                                                                             \
    _Pragma("unroll")                                                             \
    for (int fn = 0; fn < 4; ++fn) {                                              \
      const int n = wn * 64 + fn * 16 + lcol;                                     \
      bfr[fn] = *(const bf16x8*)(smem + (BUF) + 16384 + n * 64 + (((lk ^ ((n >> 1) & 3)) & 3) << 4)); \
    }                                                                             \
    _Pragma("unroll")                                                             \
    for (int fm = 0; fm < 4; ++fm)                                                \
      _Pragma("unroll")                                                           \
      for (int fn = 0; fn < 4; ++fn)                                              \
        acc[fm][fn] = __builtin_amdgcn_mfma_f32_16x16x32_bf16(af[fm], bfr[fn], acc[fm][fn], 0, 0, 0); \
  } while (0)

  const int kb = kbeg * 32;
  STAGE_D(0, kb);
  for (int it = 0; it < 21; ++it) {
    STAGE_D(24576, kb + (2 * it + 1) * 32);
    VWAIT_BAR(3);
    COMPUTE_D(0);
    VBAR();
    STAGE_D(0, kb + (2 * it + 2) * 32);
    VWAIT_BAR(3);
    COMPUTE_D(24576);
    VBAR();
  }
  STAGE_D(24576, kb + 43 * 32);
  VWAIT_BAR(3);
  COMPUTE_D(0);
  VBAR();
  VWAIT_BAR(0);
  COMPUTE_D(24576);
#undef STAGE_D
#undef COMPUTE_D

  #pragma unroll
  for (int fm = 0; fm < 4; ++fm) {
    #pragma unroll
    for (int fn = 0; fn < 4; ++fn) {
      const int col = n0 + wn * 64 + fn * 16 + lcol;
      #pragma unroll
      for (int r = 0; r < 4; ++r) {
        const int lrow = wm * 64 + fm * 16 + lk * 4 + r;
        if (lrow < mcnt) {
          const float v = acc[fm][fn][r];
          const int sl = rowbase + lrow;
          const int orow = em ? list[sl] : sl;
          const float sc = em ? wl[sl] : sg[sl];
          atomicAdd(out + (size_t)orow * HDIM + col, sc * v);
        }
      }
    }
  }
}

extern "C" void kernel_launch(void* const* d_in, const int* in_sizes, int n_in,
                              void* d_out, int out_size, void* d_ws, size_t ws_size,
                              hipStream_t stream)
{
  const float* x       = (const float*)d_in[0];
  const float* gate_w  = (const float*)d_in[1];
  const float* w_gate  = (const float*)d_in[2];
  const float* w_up    = (const float*)d_in[3];
  const float* w_down  = (const float*)d_in[4];
  const float* sw_gate = (const float*)d_in[5];
  const float* sw_up   = (const float*)d_in[6];
  const float* sw_down = (const float*)d_in[7];
  const float* sgw     = (const float*)d_in[8];

  float* out = (float*)d_out;   // f32 [TOK][H]; pure accumulator (zeroed)
  char* ws = (char*)d_ws;

  const size_t NEED_OVL   = 251100000;   // all-weights layout (~251 MB)
  const size_t NEED_FUSED = 182000000;   // r10 layout

  if (ws_size >= NEED_OVL) {
    unsigned short* Xb  = (unsigned short*)ws;                      //   8,388,608
    unsigned short* W1  = (unsigned short*)(ws + 8388608);          //  23,068,672 shG^T
    unsigned short* W2  = (unsigned short*)(ws + 31457280);         //  23,068,672 shU^T
    unsigned short* W3  = (unsigned short*)(ws + 54525952);         //  46,137,344 exG^T
    unsigned short* W4  = (unsigned short*)(ws + 100663296);        //  46,137,344 exU^T
    unsigned short* W5  = (unsigned short*)(ws + 146800640);        //  23,068,672 shDown^T
    unsigned short* W6  = (unsigned short*)(ws + 169869312);        //  46,137,344 exDown^T
    unsigned short* shb = (unsigned short*)(ws + 216006656);        //  23,068,672
    unsigned short* hb  = (unsigned short*)(ws + 239075328);        //  11,894,784
    char* meta = ws + 250970112;
    int*   cnt   = (int*)(meta);
    int*   cur   = (int*)(meta + 256);
    int*   offs  = (int*)(meta + 512);
    int*   list  = (int*)(meta + 768);                 // 4608 ints (zero-padded)
    float* wl    = (float*)(meta + 768 + 18432);       // 4608 floats (zero-padded)
    int*   tok_e = (int*)(meta + 768 + 2 * 18432);
    float* tok_w = (float*)(meta + 768 + 2 * 18432 + 16384);
    float* sg    = (float*)(meta + 768 + 2 * 18432 + 32768);

    hipMemsetAsync(meta, 0, 768 + 2 * 18432, stream);
    hipMemsetAsync(out, 0, (size_t)TOK * HDIM * 4, stream);

    // ONE dispatch: 25344 transpose + 1024 cvt + 2048 router blocks
    prep_all_kernel<<<28416, 256, 0, stream>>>(
        x, gate_w, sgw, sw_gate, sw_up, w_gate, w_up, sw_down, w_down,
        W1, W2, W3, W4, W5, W6, Xb, cnt, tok_e, tok_w, sg);

    scan_kernel<<<1, 64, 0, stream>>>(cnt, offs);
    build_kernel<<<8, 256, 0, stream>>>(tok_e, tok_w, offs, cur, list, wl);

    gateup_fused_kernel<<<1088, 512, 0, stream>>>(
        Xb, W1, W2, W3, W4, shb, hb, list, offs, cnt);

    down_fused_kernel<<<1536, 512, 0, stream>>>(shb, hb, W5, W6, out, list, wl, sg, offs, cnt);
  } else if (ws_size >= NEED_FUSED) {
    // r10 layout: down-weight transposes overwrite W1/W3 after gateup
    unsigned short* Xb  = (unsigned short*)ws;
    unsigned short* W1  = (unsigned short*)(ws + 8388608);
    unsigned short* W2  = (unsigned short*)(ws + 31457280);
    unsigned short* W3  = (unsigned short*)(ws + 54525952);
    unsigned short* W4  = (unsigned short*)(ws + 100663296);
    unsigned short* shb = (unsigned short*)(ws + 146800640);
    unsigned short* hb  = (unsigned short*)(ws + 169869312);
    char* meta = ws + 181764096;
    int*   cnt   = (int*)(meta);
    int*   cur   = (int*)(meta + 256);
    int*   offs  = (int*)(meta + 512);
    int*   list  = (int*)(meta + 768);
    float* wl    = (float*)(meta + 768 + 18432);
    int*   tok_e = (int*)(meta + 768 + 2 * 18432);
    float* tok_w = (float*)(meta + 768 + 2 * 18432 + 16384);
    float* sg    = (float*)(meta + 768 + 2 * 18432 + 32768);

    hipMemsetAsync(meta, 0, 768 + 2 * 18432, stream);
    hipMemsetAsync(out, 0, (size_t)TOK * HDIM * 4, stream);

    cvt_kernel<<<TOK * HDIM / 4 / 512, 256, 0, stream>>>(x, Xb, TOK * HDIM / 4);
    router_kernel<<<TOK, 256, 0, stream>>>(x, gate_w, sgw, cnt, tok_e, tok_w, sg);
    scan_kernel<<<1, 64, 0, stream>>>(cnt, offs);
    build_kernel<<<8, 256, 0, stream>>>(tok_e, tok_w, offs, cur, list, wl);

    transpose_cvt_kernel<<<dim3(ISDIM / 64, HDIM / 64, 1), 256, 0, stream>>>(sw_gate, W1, HDIM, ISDIM);
    transpose_cvt_kernel<<<dim3(ISDIM / 64, HDIM / 64, 1), 256, 0, stream>>>(sw_up,   W2, HDIM, ISDIM);
    transpose_cvt_kernel<<<dim3(IDIM / 64, HDIM / 64, NEXP), 256, 0, stream>>>(w_gate, W3, HDIM, IDIM);
    transpose_cvt_kernel<<<dim3(IDIM / 64, HDIM / 64, NEXP), 256, 0, stream>>>(w_up,   W4, HDIM, IDIM);

    gateup_fused_kernel<<<1088, 512, 0, stream>>>(
        Xb, W1, W2, W3, W4, shb, hb, list, offs, cnt);

    transpose_cvt_kernel<<<dim3(HDIM / 64, ISDIM / 64, 1), 256, 0, stream>>>(sw_down, W1, ISDIM, HDIM);
    transpose_cvt_kernel<<<dim3(HDIM / 64, IDIM / 64, NEXP), 256, 0, stream>>>(w_down, W3, IDIM, HDIM);

    down_fused_kernel<<<1536, 512, 0, stream>>>(shb, hb, W1, W3, out, list, wl, sg, offs, cnt);
  }
}

// Round 17
// 570.432 us; speedup vs baseline: 1.0568x; 1.0032x over previous
//
#include <hip/hip_runtime.h>
#include <hip/hip_bf16.h>
#include <stdint.h>

// Qwen3.5 MoE block: router top-2 sparse dispatch + shared expert (SwiGLU), bf16 MFMA.
// B=2,S=1024 -> TOK=2048 tokens. H=2048, I=1408, IS=5632, E=8, K=2. Output f32.
// Round 17: r16 (best: 572us) + scan merged into build (each block computes the
// 8-wide prefix from cnt locally) -> one fewer serial dispatch. GEMMs/prep exact.
#define TOK   2048
#define HDIM  2048
#define IDIM  1408
#define ISDIM 5632
#define NEXP  8

typedef float  f32x4  __attribute__((ext_vector_type(4)));
typedef short  bf16x8 __attribute__((ext_vector_type(8)));

__device__ __forceinline__ unsigned short f2b(float f) {
  union { float f; uint32_t u; } v; v.f = f;
  return (unsigned short)((v.u + 0x7fffu + ((v.u >> 16) & 1u)) >> 16); // RNE
}

// async global->LDS DMA, 16 B per lane: LDS dest wave-uniform base + lane*16.
__device__ __forceinline__ void async16(void* lds, const void* g) {
  __builtin_amdgcn_global_load_lds(
      (const __attribute__((address_space(1))) unsigned int*)g,
      (__attribute__((address_space(3))) unsigned int*)lds, 16, 0, 0);
}

// counted-vmcnt + raw barrier (no lgkm/vm drain); "memory" clobber pins LDS/VMEM ops.
#define VWAIT_BAR(N) asm volatile("s_waitcnt vmcnt(" #N ")\n\ts_barrier" ::: "memory")
#define VBAR()       asm volatile("s_barrier" ::: "memory")

// ---------------- router (standalone, for fallback path) ----------------
__global__ __launch_bounds__(256) void router_kernel(
    const float* __restrict__ X, const float* __restrict__ GW,
    const float* __restrict__ SGW, int* __restrict__ cnt,
    int* __restrict__ tok_e, float* __restrict__ tok_w, float* __restrict__ sg)
{
  const int tkn = blockIdx.x, t = threadIdx.x;
  const float* xr = X + (size_t)tkn * HDIM;
  float a[NEXP + 1];
  #pragma unroll
  for (int e = 0; e <= NEXP; ++e) a[e] = 0.f;
  for (int h = t; h < HDIM; h += 256) {
    const float xv = xr[h];
    #pragma unroll
    for (int e = 0; e < NEXP; ++e) a[e] += xv * GW[e * HDIM + h];
    a[NEXP] += xv * SGW[h];
  }
  #pragma unroll
  for (int off = 32; off > 0; off >>= 1) {
    #pragma unroll
    for (int e = 0; e <= NEXP; ++e) a[e] += __shfl_down(a[e], off);
  }
  __shared__ float red[4][NEXP + 1];
  if ((t & 63) == 0) {
    #pragma unroll
    for (int e = 0; e <= NEXP; ++e) red[t >> 6][e] = a[e];
  }
  __syncthreads();
  if (t == 0) {
    float l[NEXP + 1];
    #pragma unroll
    for (int e = 0; e <= NEXP; ++e) l[e] = red[0][e] + red[1][e] + red[2][e] + red[3][e];
    int i1 = 0;
    #pragma unroll
    for (int e = 1; e < NEXP; ++e) if (l[e] > l[i1]) i1 = e;
    int i2 = (i1 == 0) ? 1 : 0;
    #pragma unroll
    for (int e = 0; e < NEXP; ++e) if (e != i1 && e != i2 && l[e] > l[i2]) i2 = e;
    const float w1 = 1.f / (1.f + __expf(l[i2] - l[i1]));   // softmax+top2+renorm == sigmoid(diff)
    tok_e[tkn * 2 + 0] = i1; tok_e[tkn * 2 + 1] = i2;
    tok_w[tkn * 2 + 0] = w1; tok_w[tkn * 2 + 1] = 1.f - w1;
    atomicAdd(&cnt[i1], 1); atomicAdd(&cnt[i2], 1);
    sg[tkn] = 1.f / (1.f + __expf(-l[NEXP]));
  }
}

// build with inlined scan: each block derives offs from cnt (8-wide prefix).
__global__ __launch_bounds__(256) void build_kernel(
    const int* __restrict__ cnt,
    const int* __restrict__ tok_e, const float* __restrict__ tok_w,
    int* __restrict__ offs_out, int* __restrict__ cur,
    int* __restrict__ list, float* __restrict__ wl)
{
  __shared__ int offs[NEXP];
  if (threadIdx.x < NEXP) {
    int r = 0;
    #pragma unroll
    for (int e = 0; e < NEXP; ++e) { if (e == (int)threadIdx.x) break; r += cnt[e]; }
    // simpler: compute prefix serially per lane
    int acc2 = 0;
    for (int e = 0; e < (int)threadIdx.x; ++e) acc2 += cnt[e];
    offs[threadIdx.x] = acc2;
    if (blockIdx.x == 0) offs_out[threadIdx.x] = acc2;   // publish for GEMMs
    (void)r;
  }
  __syncthreads();
  const int tkn = blockIdx.x * 256 + threadIdx.x;
  if (tkn >= TOK) return;
  #pragma unroll
  for (int k = 0; k < 2; ++k) {
    const int e = tok_e[tkn * 2 + k];
    const int pos = atomicAdd(&cur[e], 1);
    const int slot = offs[e] + pos;
    list[slot] = tkn;
    wl[slot] = tok_w[tkn * 2 + k];
  }
}

// ---------------- preprocessing (standalone, for fallback path) ----------------
__global__ __launch_bounds__(256) void cvt_kernel(
    const float* __restrict__ src, unsigned short* __restrict__ dst, int n4)
{
  const int i = blockIdx.x * 512 + threadIdx.x;
  #pragma unroll
  for (int p = 0; p < 2; ++p) {
    const int j = i + p * 256;
    if (j < n4) {
      const float4 v = ((const float4*)src)[j];
      ushort4 b; b.x = f2b(v.x); b.y = f2b(v.y); b.z = f2b(v.z); b.w = f2b(v.w);
      ((ushort4*)dst)[j] = b;
    }
  }
}

// legacy single-matrix transpose (fallback path). f32 [R][C] -> bf16 [C][R].
__global__ __launch_bounds__(256) void transpose_cvt_kernel(
    const float* __restrict__ src, unsigned short* __restrict__ dst,
    const int R, const int C)
{
  __shared__ unsigned short tile[64][72];
  const size_t mat = (size_t)blockIdx.z * R * C;
  const int c0 = blockIdx.x * 64, r0 = blockIdx.y * 64;
  const int t = threadIdx.x;
  const int rr = t >> 4, cc = (t & 15) * 4;
  #pragma unroll
  for (int p = 0; p < 4; ++p) {
    const int r = rr + p * 16;
    const float4 v = *(const float4*)(src + mat + (size_t)(r0 + r) * C + c0 + cc);
    tile[cc + 0][r] = f2b(v.x);
    tile[cc + 1][r] = f2b(v.y);
    tile[cc + 2][r] = f2b(v.z);
    tile[cc + 3][r] = f2b(v.w);
  }
  __syncthreads();
  #pragma unroll
  for (int p = 0; p < 2; ++p) {
    const int id = p * 256 + t;
    const int c = id >> 3, q = id & 7;
    const uint4 v = *(const uint4*)&tile[c][q * 8];
    *(uint4*)(dst + mat + (size_t)(c0 + c) * R + r0 + q * 8) = v;
  }
}

// ---------------- unified preprocessing: 6 transposes + X cvt + router ----------------
// blocks [0,25344): weight transposes; [25344,26368): X cvt; [26368,28416): router.
__global__ __launch_bounds__(256) void prep_all_kernel(
    const float* __restrict__ Xf,
    const float* __restrict__ gate_w, const float* __restrict__ sgw,
    const float* __restrict__ sw_gate, const float* __restrict__ sw_up,
    const float* __restrict__ w_gate,  const float* __restrict__ w_up,
    const float* __restrict__ sw_down, const float* __restrict__ w_down,
    unsigned short* __restrict__ W1, unsigned short* __restrict__ W2,
    unsigned short* __restrict__ W3, unsigned short* __restrict__ W4,
    unsigned short* __restrict__ W5, unsigned short* __restrict__ W6,
    unsigned short* __restrict__ Xb,
    int* __restrict__ cnt, int* __restrict__ tok_e,
    float* __restrict__ tok_w, float* __restrict__ sg)
{
  const int t = threadIdx.x;

  if (blockIdx.x >= 26368) {
    // ---------- router ----------
    const int tkn = blockIdx.x - 26368;
    const float* xr = Xf + (size_t)tkn * HDIM;
    float a[NEXP + 1];
    #pragma unroll
    for (int e = 0; e <= NEXP; ++e) a[e] = 0.f;
    for (int h = t; h < HDIM; h += 256) {
      const float xv = xr[h];
      #pragma unroll
      for (int e = 0; e < NEXP; ++e) a[e] += xv * gate_w[e * HDIM + h];
      a[NEXP] += xv * sgw[h];
    }
    #pragma unroll
    for (int off = 32; off > 0; off >>= 1) {
      #pragma unroll
      for (int e = 0; e <= NEXP; ++e) a[e] += __shfl_down(a[e], off);
    }
    __shared__ float red[4][NEXP + 1];
    if ((t & 63) == 0) {
      #pragma unroll
      for (int e = 0; e <= NEXP; ++e) red[t >> 6][e] = a[e];
    }
    __syncthreads();
    if (t == 0) {
      float l[NEXP + 1];
      #pragma unroll
      for (int e = 0; e <= NEXP; ++e) l[e] = red[0][e] + red[1][e] + red[2][e] + red[3][e];
      int i1 = 0;
      #pragma unroll
      for (int e = 1; e < NEXP; ++e) if (l[e] > l[i1]) i1 = e;
      int i2 = (i1 == 0) ? 1 : 0;
      #pragma unroll
      for (int e = 0; e < NEXP; ++e) if (e != i1 && e != i2 && l[e] > l[i2]) i2 = e;
      const float w1 = 1.f / (1.f + __expf(l[i2] - l[i1]));
      tok_e[tkn * 2 + 0] = i1; tok_e[tkn * 2 + 1] = i2;
      tok_w[tkn * 2 + 0] = w1; tok_w[tkn * 2 + 1] = 1.f - w1;
      atomicAdd(&cnt[i1], 1); atomicAdd(&cnt[i2], 1);
      sg[tkn] = 1.f / (1.f + __expf(-l[NEXP]));
    }
    return;
  }

  if (blockIdx.x >= 25344) {
    // ---------- X cvt: 1024 blocks x (256 thr x 4 float4) ----------
    const int gi = (blockIdx.x - 25344) * 256 + t;
    #pragma unroll
    for (int p = 0; p < 4; ++p) {
      const int j = gi + p * 262144;           // 1,048,576 float4 total
      const float4 v = ((const float4*)Xf)[j];
      ushort4 b; b.x = f2b(v.x); b.y = f2b(v.y); b.z = f2b(v.z); b.w = f2b(v.w);
      ((ushort4*)Xb)[j] = b;
    }
    return;
  }

  // ---------- weight transposes ----------
  __shared__ unsigned short tile[64][72];
  int b = blockIdx.x;
  const float* src; unsigned short* dst;
  int srcC, dstLen, cx, ry;
  if (b < 2816)       { src = sw_gate; dst = W1; srcC = ISDIM; dstLen = HDIM; cx = b % 88; ry = b / 88; }
  else if (b < 5632)  { b -= 2816; src = sw_up; dst = W2; srcC = ISDIM; dstLen = HDIM; cx = b % 88; ry = b / 88; }
  else if (b < 11264) { b -= 5632; const int e = b / 704, r = b % 704;
                        src = w_gate + (size_t)e * HDIM * IDIM; dst = W3 + (size_t)e * IDIM * HDIM;
                        srcC = IDIM; dstLen = HDIM; cx = r % 22; ry = r / 22; }
  else if (b < 16896) { b -= 11264; const int e = b / 704, r = b % 704;
                        src = w_up + (size_t)e * HDIM * IDIM; dst = W4 + (size_t)e * IDIM * HDIM;
                        srcC = IDIM; dstLen = HDIM; cx = r % 22; ry = r / 22; }
  else if (b < 19712) { b -= 16896; src = sw_down; dst = W5; srcC = HDIM; dstLen = ISDIM; cx = b % 32; ry = b / 32; }
  else                { b -= 19712; const int e = b / 704, r = b % 704;
                        src = w_down + (size_t)e * IDIM * HDIM; dst = W6 + (size_t)e * HDIM * IDIM;
                        srcC = HDIM; dstLen = IDIM; cx = r % 32; ry = r / 32; }

  const int c0 = cx * 64, r0 = ry * 64;
  const int rr = t >> 4, cc = (t & 15) * 4;
  #pragma unroll
  for (int p = 0; p < 4; ++p) {
    const int r = rr + p * 16;
    const float4 v = *(const float4*)(src + (size_t)(r0 + r) * srcC + c0 + cc);
    tile[cc + 0][r] = f2b(v.x);
    tile[cc + 1][r] = f2b(v.y);
    tile[cc + 2][r] = f2b(v.z);
    tile[cc + 3][r] = f2b(v.w);
  }
  __syncthreads();
  #pragma unroll
  for (int p = 0; p < 2; ++p) {
    const int id = p * 256 + t;
    const int ci = id >> 3, q = id & 7;
    *(uint4*)(dst + (size_t)(c0 + ci) * dstLen + r0 + q * 8) = *(const uint4*)&tile[ci][q * 8];
  }
}

// ---------------- FUSED gateup: 256x128 tile, 8 waves, BK=32, counted-vmcnt dbuf (r10) ----------------
__global__ __launch_bounds__(512) void gateup_fused_kernel(
    const unsigned short* __restrict__ Xb,
    const unsigned short* __restrict__ Wshg, const unsigned short* __restrict__ Wshu,
    const unsigned short* __restrict__ Wexg, const unsigned short* __restrict__ Wexu,
    unsigned short* __restrict__ shb, unsigned short* __restrict__ hb,
    const int* __restrict__ list, const int* __restrict__ offs, const int* __restrict__ cnt)
{
  __shared__ char smem[65536];

  const int xcd = blockIdx.x & 7;
  const int local = blockIdx.x >> 3;
  const int c = xcd + 8 * (local >> 3);
  const int mt = local & 7;
  if (c >= 132) return;
  const int t = threadIdx.x;

  int rowbase, mcnt, n0, N, gather;
  const unsigned short *Wg, *Wu;
  unsigned short* Cout;
  if (c < 44) {
    N = ISDIM; n0 = c * 128; rowbase = mt * 256; mcnt = 256; gather = 0;
    Wg = Wshg; Wu = Wshu; Cout = shb;
  } else {
    const int cE = c - 44;
    const int e = cE / 11, n = cE % 11;
    mcnt = cnt[e] - mt * 256;
    if (mcnt <= 0) return;
    N = IDIM; n0 = n * 128; rowbase = offs[e] + mt * 256; gather = 1;
    Wg = Wexg + (size_t)e * IDIM * HDIM;
    Wu = Wexu + (size_t)e * IDIM * HDIM;
    Cout = hb;
  }

  const int wid = t >> 6, lane = t & 63;
  const int wm = wid >> 1, wn = wid & 1;
  const int lcol = lane & 15, lk = lane >> 4;

  f32x4 accg[4][4], accu[4][4];
  #pragma unroll
  for (int i = 0; i < 4; ++i)
    #pragma unroll
    for (int j = 0; j < 4; ++j) { accg[i][j] = {0.f,0.f,0.f,0.f}; accu[i][j] = {0.f,0.f,0.f,0.f}; }

  int arow[2], akoff[2];
  #pragma unroll
  for (int p = 0; p < 2; ++p) {
    const int s = p * 512 + t;
    const int m = s >> 2;
    akoff[p] = (((s & 3) ^ ((m >> 1) & 3)) << 3);
    arow[p] = gather ? list[rowbase + m] : (rowbase + m);   // list zero-padded (4608)
  }
  const int albase0 = (t & 448) * 16;
  const int albase1 = (512 + (t & 448)) * 16;
  const int bmrow = n0 + (t >> 2);
  const int bkoff = (((t & 3) ^ (((t >> 2) >> 1) & 3)) << 3);
  const int blbase = (t & 448) * 16;

#define STAGE_GU(BUF, K0) do {                                                    \
    async16(smem + (BUF) + albase0,        Xb + (size_t)arow[0] * HDIM + (K0) + akoff[0]); \
    async16(smem + (BUF) + albase1,        Xb + (size_t)arow[1] * HDIM + (K0) + akoff[1]); \
    async16(smem + (BUF) + 16384 + blbase, Wg + (size_t)bmrow * HDIM + (K0) + bkoff); \
    async16(smem + (BUF) + 24576 + blbase, Wu + (size_t)bmrow * HDIM + (K0) + bkoff); \
  } while (0)

#define COMPUTE_GU(BUF) do {                                                      \
    bf16x8 af[4], bg[4], bu[4];                                                   \
    _Pragma("unroll")                                                             \
    for (int fm = 0; fm < 4; ++fm) {                                              \
      const int m = wm * 64 + fm * 16 + lcol;                                     \
      af[fm] = *(const bf16x8*)(smem + (BUF) + m * 64 + (((lk ^ ((m >> 1) & 3)) & 3) << 4)); \
    }                                                                             \
    _Pragma("unroll")                                                             \
    for (int fn = 0; fn < 4; ++fn) {                                              \
      const int n = wn * 64 + fn * 16 + lcol;                                     \
      const int ra = n * 64 + (((lk ^ ((n >> 1) & 3)) & 3) << 4);                 \
      bg[fn] = *(const bf16x8*)(smem + (BUF) + 16384 + ra);                       \
      bu[fn] = *(const bf16x8*)(smem + (BUF) + 24576 + ra);                       \
    }                                                                             \
    _Pragma("unroll")                                                             \
    for (int fm = 0; fm < 4; ++fm)                                                \
      _Pragma("unroll")                                                           \
      for (int fn = 0; fn < 4; ++fn) {                                            \
        accg[fm][fn] = __builtin_amdgcn_mfma_f32_16x16x32_bf16(af[fm], bg[fn], accg[fm][fn], 0, 0, 0); \
        accu[fm][fn] = __builtin_amdgcn_mfma_f32_16x16x32_bf16(af[fm], bu[fn], accu[fm][fn], 0, 0, 0); \
      } } while (0)

  STAGE_GU(0, 0);
  for (int it = 0; it < 31; ++it) {
    STAGE_GU(32768, (2 * it + 1) * 32);
    VWAIT_BAR(4);
    COMPUTE_GU(0);
    VBAR();
    STAGE_GU(0, (2 * it + 2) * 32);
    VWAIT_BAR(4);
    COMPUTE_GU(32768);
    VBAR();
  }
  STAGE_GU(32768, 63 * 32);
  VWAIT_BAR(4);
  COMPUTE_GU(0);
  VBAR();
  VWAIT_BAR(0);
  COMPUTE_GU(32768);
#undef STAGE_GU
#undef COMPUTE_GU

  #pragma unroll
  for (int fm = 0; fm < 4; ++fm) {
    #pragma unroll
    for (int fn = 0; fn < 4; ++fn) {
      const int col = n0 + wn * 64 + fn * 16 + lcol;
      #pragma unroll
      for (int r = 0; r < 4; ++r) {
        const int lrow = wm * 64 + fm * 16 + lk * 4 + r;
        if (lrow < mcnt) {
          const float gv = accg[fm][fn][r];
          const float uv = accu[fm][fn][r];
          const float hv = gv * uv / (1.f + __expf(-gv));
          Cout[(size_t)(rowbase + lrow) * N + col] = f2b(hv);
        }
      }
    }
  }
}

// ---------------- FUSED down: r10 verbatim (256x128, 2-buffer 48KB, vmcnt(3)) ----------------
__global__ __launch_bounds__(512) void down_fused_kernel(
    const unsigned short* __restrict__ shb, const unsigned short* __restrict__ hb,
    const unsigned short* __restrict__ WdshT, const unsigned short* __restrict__ WdexT,
    float* __restrict__ out,
    const int* __restrict__ list, const float* __restrict__ wl, const float* __restrict__ sg,
    const int* __restrict__ offs, const int* __restrict__ cnt)
{
  __shared__ char smem[49152];

  const int xcd = blockIdx.x & 7;
  const int local = blockIdx.x >> 3;
  const int c = xcd + 8 * (local >> 3);   // 0..191
  const int mt = local & 7;
  const int t = threadIdx.x;

  int rowbase, mcnt, n0, K, kbeg, em;
  const unsigned short *Ap, *Bp;
  if (c < 64) {                // shared, splitK=4 (44 steps each)
    const int pn = c & 15, ksp = c >> 4;
    rowbase = mt * 256; mcnt = 256; n0 = pn * 128;
    K = ISDIM; kbeg = ksp * 44; em = 0;
    Ap = shb; Bp = WdshT;
  } else {                     // expert (44 steps)
    const int cE = c - 64;
    const int e = cE >> 4, n = cE & 15;
    mcnt = cnt[e] - mt * 256;
    if (mcnt <= 0) return;
    rowbase = offs[e] + mt * 256; n0 = n * 128;
    K = IDIM; kbeg = 0; em = 1;
    Ap = hb; Bp = WdexT + (size_t)e * HDIM * IDIM;
  }

  const int wid = t >> 6, lane = t & 63;
  const int wm = wid >> 1, wn = wid & 1;
  const int lcol = lane & 15, lk = lane >> 4;

  f32x4 acc[4][4];
  #pragma unroll
  for (int i = 0; i < 4; ++i)
    #pragma unroll
    for (int j = 0; j < 4; ++j) acc[i][j] = {0.f,0.f,0.f,0.f};

  int amrow[2], akoff[2];
  #pragma unroll
  for (int p = 0; p < 2; ++p) {
    const int s = p * 512 + t;
    const int m = s >> 2;
    akoff[p] = (((s & 3) ^ ((m >> 1) & 3)) << 3);
    int rw = rowbase + m;
    if (em && rw > 4223) rw = 4223;    // clamp: hb has 4224 row slots
    amrow[p] = rw;
  }
  const int albase0 = (t & 448) * 16;
  const int albase1 = (512 + (t & 448)) * 16;
  const int bmrow = n0 + (t >> 2);
  const int bkoff = (((t & 3) ^ (((t >> 2) >> 1) & 3)) << 3);
  const int blbase = (t & 448) * 16;

#define STAGE_D(BUF, K0) do {                                                     \
    async16(smem + (BUF) + albase0,        Ap + (size_t)amrow[0] * K + (K0) + akoff[0]); \
    async16(smem + (BUF) + albase1,        Ap + (size_t)amrow[1] * K + (K0) + akoff[1]); \
    async16(smem + (BUF) + 16384 + blbase, Bp + (size_t)bmrow * K + (K0) + bkoff); \
  } while (0)

#define COMPUTE_D(BUF) do {                                                       \
    bf16x8 af[4], bfr[4];                                                         \
    _Pragma("unroll")                                                             \
    for (int fm = 0; fm < 4; ++fm) {                                              \
      const int m = wm * 64 + fm * 16 + lcol;                                     \
      af[fm] = *(const bf16x8*)(smem + (BUF) + m * 64 + (((lk ^ ((m >> 1) & 3)) & 3) << 4)); \
    }                                                                             \
    _Pragma("unroll")                                                             \
    for (int fn = 0; fn < 4; ++fn) {                                              \
      const int n = wn * 64 + fn * 16 + lcol;                                     \
      bfr[fn] = *(const bf16x8*)(smem + (BUF) + 16384 + n * 64 + (((lk ^ ((n >> 1) & 3)) & 3) << 4)); \
    }                                                                             \
    _Pragma("unroll")                                                             \
    for (int fm = 0; fm < 4; ++fm)                                                \
      _Pragma("unroll")                                                           \
      for (int fn = 0; fn < 4; ++fn)                                              \
        acc[fm][fn] = __builtin_amdgcn_mfma_f32_16x16x32_bf16(af[fm], bfr[fn], acc[fm][fn], 0, 0, 0); \
  } while (0)

  const int kb = kbeg * 32;
  STAGE_D(0, kb);
  for (int it = 0; it < 21; ++it) {
    STAGE_D(24576, kb + (2 * it + 1) * 32);
    VWAIT_BAR(3);
    COMPUTE_D(0);
    VBAR();
    STAGE_D(0, kb + (2 * it + 2) * 32);
    VWAIT_BAR(3);
    COMPUTE_D(24576);
    VBAR();
  }
  STAGE_D(24576, kb + 43 * 32);
  VWAIT_BAR(3);
  COMPUTE_D(0);
  VBAR();
  VWAIT_BAR(0);
  COMPUTE_D(24576);
#undef STAGE_D
#undef COMPUTE_D

  #pragma unroll
  for (int fm = 0; fm < 4; ++fm) {
    #pragma unroll
    for (int fn = 0; fn < 4; ++fn) {
      const int col = n0 + wn * 64 + fn * 16 + lcol;
      #pragma unroll
      for (int r = 0; r < 4; ++r) {
        const int lrow = wm * 64 + fm * 16 + lk * 4 + r;
        if (lrow < mcnt) {
          const float v = acc[fm][fn][r];
          const int sl = rowbase + lrow;
          const int orow = em ? list[sl] : sl;
          const float sc = em ? wl[sl] : sg[sl];
          atomicAdd(out + (size_t)orow * HDIM + col, sc * v);
        }
      }
    }
  }
}

extern "C" void kernel_launch(void* const* d_in, const int* in_sizes, int n_in,
                              void* d_out, int out_size, void* d_ws, size_t ws_size,
                              hipStream_t stream)
{
  const float* x       = (const float*)d_in[0];
  const float* gate_w  = (const float*)d_in[1];
  const float* w_gate  = (const float*)d_in[2];
  const float* w_up    = (const float*)d_in[3];
  const float* w_down  = (const float*)d_in[4];
  const float* sw_gate = (const float*)d_in[5];
  const float* sw_up   = (const float*)d_in[6];
  const float* sw_down = (const float*)d_in[7];
  const float* sgw     = (const float*)d_in[8];

  float* out = (float*)d_out;   // f32 [TOK][H]; pure accumulator (zeroed)
  char* ws = (char*)d_ws;

  const size_t NEED_OVL   = 251100000;   // all-weights layout (~251 MB)
  const size_t NEED_FUSED = 182000000;   // r10 layout

  if (ws_size >= NEED_OVL) {
    unsigned short* Xb  = (unsigned short*)ws;                      //   8,388,608
    unsigned short* W1  = (unsigned short*)(ws + 8388608);          //  23,068,672 shG^T
    unsigned short* W2  = (unsigned short*)(ws + 31457280);         //  23,068,672 shU^T
    unsigned short* W3  = (unsigned short*)(ws + 54525952);         //  46,137,344 exG^T
    unsigned short* W4  = (unsigned short*)(ws + 100663296);        //  46,137,344 exU^T
    unsigned short* W5  = (unsigned short*)(ws + 146800640);        //  23,068,672 shDown^T
    unsigned short* W6  = (unsigned short*)(ws + 169869312);        //  46,137,344 exDown^T
    unsigned short* shb = (unsigned short*)(ws + 216006656);        //  23,068,672
    unsigned short* hb  = (unsigned short*)(ws + 239075328);        //  11,894,784
    char* meta = ws + 250970112;
    int*   cnt   = (int*)(meta);
    int*   cur   = (int*)(meta + 256);
    int*   offs  = (int*)(meta + 512);
    int*   list  = (int*)(meta + 768);                 // 4608 ints (zero-padded)
    float* wl    = (float*)(meta + 768 + 18432);       // 4608 floats (zero-padded)
    int*   tok_e = (int*)(meta + 768 + 2 * 18432);
    float* tok_w = (float*)(meta + 768 + 2 * 18432 + 16384);
    float* sg    = (float*)(meta + 768 + 2 * 18432 + 32768);

    hipMemsetAsync(meta, 0, 768 + 2 * 18432, stream);
    hipMemsetAsync(out, 0, (size_t)TOK * HDIM * 4, stream);

    // ONE dispatch: 25344 transpose + 1024 cvt + 2048 router blocks
    prep_all_kernel<<<28416, 256, 0, stream>>>(
        x, gate_w, sgw, sw_gate, sw_up, w_gate, w_up, sw_down, w_down,
        W1, W2, W3, W4, W5, W6, Xb, cnt, tok_e, tok_w, sg);

    // build with inlined scan (offs computed per block from cnt)
    build_kernel<<<8, 256, 0, stream>>>(cnt, tok_e, tok_w, offs, cur, list, wl);

    gateup_fused_kernel<<<1088, 512, 0, stream>>>(
        Xb, W1, W2, W3, W4, shb, hb, list, offs, cnt);

    down_fused_kernel<<<1536, 512, 0, stream>>>(shb, hb, W5, W6, out, list, wl, sg, offs, cnt);
  } else if (ws_size >= NEED_FUSED) {
    // r10 layout: down-weight transposes overwrite W1/W3 after gateup
    unsigned short* Xb  = (unsigned short*)ws;
    unsigned short* W1  = (unsigned short*)(ws + 8388608);
    unsigned short* W2  = (unsigned short*)(ws + 31457280);
    unsigned short* W3  = (unsigned short*)(ws + 54525952);
    unsigned short* W4  = (unsigned short*)(ws + 100663296);
    unsigned short* shb = (unsigned short*)(ws + 146800640);
    unsigned short* hb  = (unsigned short*)(ws + 169869312);
    char* meta = ws + 181764096;
    int*   cnt   = (int*)(meta);
    int*   cur   = (int*)(meta + 256);
    int*   offs  = (int*)(meta + 512);
    int*   list  = (int*)(meta + 768);
    float* wl    = (float*)(meta + 768 + 18432);
    int*   tok_e = (int*)(meta + 768 + 2 * 18432);
    float* tok_w = (float*)(meta + 768 + 2 * 18432 + 16384);
    float* sg    = (float*)(meta + 768 + 2 * 18432 + 32768);

    hipMemsetAsync(meta, 0, 768 + 2 * 18432, stream);
    hipMemsetAsync(out, 0, (size_t)TOK * HDIM * 4, stream);

    cvt_kernel<<<TOK * HDIM / 4 / 512, 256, 0, stream>>>(x, Xb, TOK * HDIM / 4);
    router_kernel<<<TOK, 256, 0, stream>>>(x, gate_w, sgw, cnt, tok_e, tok_w, sg);
    build_kernel<<<8, 256, 0, stream>>>(cnt, tok_e, tok_w, offs, cur, list, wl);

    transpose_cvt_kernel<<<dim3(ISDIM / 64, HDIM / 64, 1), 256, 0, stream>>>(sw_gate, W1, HDIM, ISDIM);
    transpose_cvt_kernel<<<dim3(ISDIM / 64, HDIM / 64, 1), 256, 0, stream>>>(sw_up,   W2, HDIM, ISDIM);
    transpose_cvt_kernel<<<dim3(IDIM / 64, HDIM / 64, NEXP), 256, 0, stream>>>(w_gate, W3, HDIM, IDIM);
    transpose_cvt_kernel<<<dim3(IDIM / 64, HDIM / 64, NEXP), 256, 0, stream>>>(w_up,   W4, HDIM, IDIM);

    gateup_fused_kernel<<<1088, 512, 0, stream>>>(
        Xb, W1, W2, W3, W4, shb, hb, list, offs, cnt);

    transpose_cvt_kernel<<<dim3(HDIM / 64, ISDIM / 64, 1), 256, 0, stream>>>(sw_down, W1, ISDIM, HDIM);
    transpose_cvt_kernel<<<dim3(HDIM / 64, IDIM / 64, NEXP), 256, 0, stream>>>(w_down, W3, IDIM, HDIM);

    down_fused_kernel<<<1536, 512, 0, stream>>>(shb, hb, W1, W3, out, list, wl, sg, offs, cnt);
  }
}